// Round 1
// baseline (485.628 us; speedup 1.0000x reference)
//
#include <hip/hip_runtime.h>
#include <hip/hip_bf16.h>

// ---------------------------------------------------------------------------
// Attention_CA: out = Proj( Softmax(mask, scale * (q Wq^T) (kv Wkv^T)_K^T) (kv Wkv^T)_V )
// B=4, N=1024, M=2048, C=768, H=12, d=64.  bf16 MFMA pipeline, fp32 accum.
// ---------------------------------------------------------------------------

typedef short  s16x8  __attribute__((ext_vector_type(8)));
typedef __bf16 bf16x8 __attribute__((ext_vector_type(8)));
typedef float  f32x4  __attribute__((ext_vector_type(4)));

#define NUM_H 12
#define DIM   768
#define BB    4
#define NQ    1024
#define MK    2048
#define QK_SCALE 0.125f  // 64^-0.5

__device__ __forceinline__ short f2b(float v) {
    __hip_bfloat16 h = __float2bfloat16(v);   // RNE
    return __builtin_bit_cast(short, h);
}

__device__ __forceinline__ f32x4 mfma16(bf16x8 a, bf16x8 b, f32x4 c) {
    return __builtin_amdgcn_mfma_f32_16x16x32_bf16(a, b, c, 0, 0, 0);
}

// ---------------------------- cast fp32 -> bf16 ----------------------------
__global__ __launch_bounds__(256) void cast_f2b_kernel(
    const float* __restrict__ s, short* __restrict__ d, int n)
{
    int i = (blockIdx.x * 256 + threadIdx.x) * 8;
    if (i >= n) return;
    float4 a = *(const float4*)(s + i);
    float4 b = *(const float4*)(s + i + 4);
    s16x8 r;
    r[0] = f2b(a.x); r[1] = f2b(a.y); r[2] = f2b(a.z); r[3] = f2b(a.w);
    r[4] = f2b(b.x); r[5] = f2b(b.y); r[6] = f2b(b.z); r[7] = f2b(b.w);
    *(s16x8*)(d + i) = r;
}

// ---------------------------- pack mask to bits ----------------------------
// mask[B,1,N,M] int32 -> bits[B,N,M/32], bit=1 means keep.
__global__ __launch_bounds__(256) void pack_mask_kernel(
    const int* __restrict__ m, unsigned* __restrict__ mb)
{
    int i = blockIdx.x * 256 + threadIdx.x;
    unsigned long long bal = __ballot(m[i] != 0);
    if ((threadIdx.x & 63) == 0) {
        int wi = i >> 5;                 // i is 64-aligned for lane 0
        mb[wi]     = (unsigned)bal;
        mb[wi + 1] = (unsigned)(bal >> 32);
    }
}

// ---------------------------- GEMM: C = A @ Bt^T ---------------------------
// A [Mrows,768] bf16 row-major, Bt [Ncols,768] bf16 row-major.
// 128x128 block tile, BK=64, 4 waves (each 64x64 = 4x4 mfma tiles).
// mode 0: qp scatter [B,H,N,d], *QK_SCALE, bf16
// mode 1: kv split -> K [B,H,M,d] bf16 (outb), V^T [B,H,d,M] bf16 (outb2)
// mode 2: out fp32 = v + bias[col]
__global__ __launch_bounds__(256) void gemm_bt_kernel(
    const short* __restrict__ A, const short* __restrict__ Bt,
    int Ncols, int mode, const float* __restrict__ bias,
    short* __restrict__ outb, short* __restrict__ outb2,
    float* __restrict__ outf)
{
    __shared__ short As[128][72];   // stride 72 shorts: 16B aligned, 2-way banks (free)
    __shared__ short Bs[128][72];
    const int K = DIM;
    int ntiles = Ncols >> 7;
    int m0 = (blockIdx.x / ntiles) << 7;
    int n0 = (blockIdx.x % ntiles) << 7;
    int t = threadIdx.x;
    int w = t >> 6, lane = t & 63, quad = lane >> 4, l16 = lane & 15;
    int wm = (w & 1) << 6, wn = (w >> 1) << 6;

    f32x4 zero4 = {0.f, 0.f, 0.f, 0.f};
    f32x4 acc[4][4];
    for (int i = 0; i < 4; i++)
        for (int j = 0; j < 4; j++) acc[i][j] = zero4;

    int lr = t >> 1;            // 0..127
    int lc = (t & 1) << 5;      // 0 or 32
    const short* Ap = A + (long)(m0 + lr) * K + lc;
    const short* Bp = Bt + (long)(n0 + lr) * K + lc;

    for (int kt = 0; kt < K; kt += 64) {
        s16x8 av0 = *(const s16x8*)(Ap + kt);
        s16x8 av1 = *(const s16x8*)(Ap + kt + 8);
        s16x8 av2 = *(const s16x8*)(Ap + kt + 16);
        s16x8 av3 = *(const s16x8*)(Ap + kt + 24);
        s16x8 bv0 = *(const s16x8*)(Bp + kt);
        s16x8 bv1 = *(const s16x8*)(Bp + kt + 8);
        s16x8 bv2 = *(const s16x8*)(Bp + kt + 16);
        s16x8 bv3 = *(const s16x8*)(Bp + kt + 24);
        __syncthreads();
        *(s16x8*)&As[lr][lc]      = av0;
        *(s16x8*)&As[lr][lc + 8]  = av1;
        *(s16x8*)&As[lr][lc + 16] = av2;
        *(s16x8*)&As[lr][lc + 24] = av3;
        *(s16x8*)&Bs[lr][lc]      = bv0;
        *(s16x8*)&Bs[lr][lc + 8]  = bv1;
        *(s16x8*)&Bs[lr][lc + 16] = bv2;
        *(s16x8*)&Bs[lr][lc + 24] = bv3;
        __syncthreads();
        for (int kh = 0; kh < 2; kh++) {
            bf16x8 af[4], bfr[4];
            for (int i = 0; i < 4; i++) {
                s16x8 tmp = *(const s16x8*)&As[wm + i * 16 + l16][kh * 32 + quad * 8];
                af[i] = __builtin_bit_cast(bf16x8, tmp);
            }
            for (int j = 0; j < 4; j++) {
                s16x8 tmp = *(const s16x8*)&Bs[wn + j * 16 + l16][kh * 32 + quad * 8];
                bfr[j] = __builtin_bit_cast(bf16x8, tmp);
            }
            for (int i = 0; i < 4; i++)
                for (int j = 0; j < 4; j++)
                    acc[i][j] = mfma16(af[i], bfr[j], acc[i][j]);
        }
    }

    for (int i = 0; i < 4; i++) {
        for (int j = 0; j < 4; j++) {
            for (int r = 0; r < 4; r++) {
                int row = m0 + wm + i * 16 + quad * 4 + r;
                int col = n0 + wn + j * 16 + l16;
                float v = acc[i][j][r];
                if (mode == 0) {
                    int b = row >> 10, n = row & 1023;
                    int h = col >> 6, dd = col & 63;
                    outb[(((long)(b * NUM_H + h) << 10) + n) * 64 + dd] = f2b(v * QK_SCALE);
                } else if (mode == 1) {
                    int b = row >> 11, m = row & 2047;
                    int two = (col >= DIM);
                    int cc = col - (two ? DIM : 0);
                    int h = cc >> 6, dd = cc & 63;
                    if (!two)
                        outb[((long)(b * NUM_H + h) * MK + m) * 64 + dd] = f2b(v);
                    else
                        outb2[((long)(b * NUM_H + h) * 64 + dd) * MK + m] = f2b(v);
                } else {
                    outf[(long)row * DIM + col] = v + bias[col];
                }
            }
        }
    }
}

// ------------------------- flash attention (bf16 MFMA) ---------------------
// grid: (b*H + h)*16 + ntile ; 64 q-rows per block, M-tiles of 64.
// Wave w owns q-rows [w*16, w*16+16). Online softmax in fp32 registers.
__global__ __launch_bounds__(256) void attn_kernel(
    const short* __restrict__ qp, const short* __restrict__ kk,
    const short* __restrict__ vt, const unsigned* __restrict__ mb,
    short* __restrict__ xb)
{
    __shared__ short qs[64][72];
    __shared__ short ks[64][72];
    __shared__ short vs[64][72];       // V^T tile: [dd][m]
    __shared__ short ps[4][16][72];    // per-wave P tile (A-layout staging)
    __shared__ unsigned mw[64][2];

    int bid = blockIdx.x;
    int nt = bid & 15;
    int bh = bid >> 4;
    int h = bh % NUM_H, b = bh / NUM_H;
    int n0 = nt << 6;
    int t = threadIdx.x, w = t >> 6, lane = t & 63, quad = lane >> 4, l16 = lane & 15;

    long hb = (long)bh;
    const short* qbase = qp + (hb * NQ + n0) * 64;
    const short* kbase = kk + hb * MK * 64;
    const short* vbase = vt + hb * 64 * MK;
    const unsigned* mbase = mb + ((long)b * NQ + n0) * 64;

    {   // load Q tile once
        int lr = t >> 2, c0 = (t & 3) << 4;
        s16x8 q0 = *(const s16x8*)(qbase + lr * 64 + c0);
        s16x8 q1 = *(const s16x8*)(qbase + lr * 64 + c0 + 8);
        *(s16x8*)&qs[lr][c0]     = q0;
        *(s16x8*)&qs[lr][c0 + 8] = q1;
    }

    f32x4 zero4 = {0.f, 0.f, 0.f, 0.f};
    f32x4 o[4];
    for (int j = 0; j < 4; j++) o[j] = zero4;
    float mst[4], lst[4];
    const float NEG_INF = -__builtin_inff();
    for (int r = 0; r < 4; r++) { mst[r] = NEG_INF; lst[r] = 0.f; }

    int lr = t >> 2, c0 = (t & 3) << 4;
    const short* kp = kbase + (long)lr * 64 + c0;
    const short* vp = vbase + (long)lr * MK + c0;

    for (int mt = 0; mt < MK; mt += 64) {
        s16x8 k0 = *(const s16x8*)(kp + (long)mt * 64);
        s16x8 k1 = *(const s16x8*)(kp + (long)mt * 64 + 8);
        s16x8 v0 = *(const s16x8*)(vp + mt);
        s16x8 v1 = *(const s16x8*)(vp + mt + 8);
        unsigned mword = 0;
        if (t < 128) mword = mbase[(t >> 1) * 64 + (mt >> 5) + (t & 1)];
        __syncthreads();   // prev iteration done reading ks/vs/ps
        *(s16x8*)&ks[lr][c0]     = k0;
        *(s16x8*)&ks[lr][c0 + 8] = k1;
        *(s16x8*)&vs[lr][c0]     = v0;
        *(s16x8*)&vs[lr][c0 + 8] = v1;
        if (t < 128) mw[t >> 1][t & 1] = mword;
        __syncthreads();

        // S = Q K^T  (16 q-rows x 64 m-cols per wave)
        f32x4 s[4];
        for (int j = 0; j < 4; j++) s[j] = zero4;
        for (int kh = 0; kh < 2; kh++) {
            s16x8 tq = *(const s16x8*)&qs[(w << 4) + l16][kh * 32 + quad * 8];
            bf16x8 aq = __builtin_bit_cast(bf16x8, tq);
            for (int j = 0; j < 4; j++) {
                s16x8 tk = *(const s16x8*)&ks[j * 16 + l16][kh * 32 + quad * 8];
                s[j] = mfma16(aq, __builtin_bit_cast(bf16x8, tk), s[j]);
            }
        }

        // mask + online softmax (row = (w*16) + quad*4 + rr, col = j*16+l16)
        for (int rr = 0; rr < 4; rr++) {
            int qrow = (w << 4) + quad * 4 + rr;
            unsigned w0 = mw[qrow][0], w1 = mw[qrow][1];
            if (!((w0 >> l16) & 1))        s[0][rr] = -9e15f;
            if (!((w0 >> (16 + l16)) & 1)) s[1][rr] = -9e15f;
            if (!((w1 >> l16) & 1))        s[2][rr] = -9e15f;
            if (!((w1 >> (16 + l16)) & 1)) s[3][rr] = -9e15f;
            float mx = fmaxf(fmaxf(s[0][rr], s[1][rr]), fmaxf(s[2][rr], s[3][rr]));
            for (int off = 1; off < 16; off <<= 1)
                mx = fmaxf(mx, __shfl_xor(mx, off, 16));
            float mnew = fmaxf(mst[rr], mx);
            float alpha = __expf(mst[rr] - mnew);   // exp(-inf)=0 first tile
            float p0 = __expf(s[0][rr] - mnew);
            float p1 = __expf(s[1][rr] - mnew);
            float p2 = __expf(s[2][rr] - mnew);
            float p3 = __expf(s[3][rr] - mnew);
            s[0][rr] = p0; s[1][rr] = p1; s[2][rr] = p2; s[3][rr] = p3;
            float rs = p0 + p1 + p2 + p3;
            for (int off = 1; off < 16; off <<= 1)
                rs += __shfl_xor(rs, off, 16);
            lst[rr] = lst[rr] * alpha + rs;
            mst[rr] = mnew;
            for (int j = 0; j < 4; j++) o[j][rr] *= alpha;
        }

        // P (C-layout) -> LDS -> A-layout
        for (int j = 0; j < 4; j++)
            for (int rr = 0; rr < 4; rr++)
                ps[w][quad * 4 + rr][j * 16 + l16] = f2b(s[j][rr]);
        __syncthreads();

        // O += P @ V   (gemm-bt with Bt = V^T tile)
        for (int kh = 0; kh < 2; kh++) {
            s16x8 tp = *(const s16x8*)&ps[w][l16][kh * 32 + quad * 8];
            bf16x8 ap = __builtin_bit_cast(bf16x8, tp);
            for (int jd = 0; jd < 4; jd++) {
                s16x8 tv = *(const s16x8*)&vs[jd * 16 + l16][kh * 32 + quad * 8];
                o[jd] = mfma16(ap, __builtin_bit_cast(bf16x8, tv), o[jd]);
            }
        }
        __syncthreads();
    }

    // epilogue: x[b, n, h*64+dd] bf16
    for (int jd = 0; jd < 4; jd++) {
        for (int rr = 0; rr < 4; rr++) {
            int qrow = n0 + (w << 4) + quad * 4 + rr;
            int col = h * 64 + jd * 16 + l16;
            xb[((long)(b * NQ) + qrow) * DIM + col] = f2b(o[jd][rr] / lst[rr]);
        }
    }
}

// ---------------------------------------------------------------------------
extern "C" void kernel_launch(void* const* d_in, const int* in_sizes, int n_in,
                              void* d_out, int out_size, void* d_ws, size_t ws_size,
                              hipStream_t stream)
{
    const float* q     = (const float*)d_in[0];   // [4,1024,768]
    const float* kv    = (const float*)d_in[1];   // [4,2048,768]
    const float* Wq    = (const float*)d_in[3-1]; // d_in[2]
    const float* Wkv   = (const float*)d_in[3];   // [1536,768]
    const float* Wproj = (const float*)d_in[4];   // [768,768]
    const float* bproj = (const float*)d_in[5];   // [768]
    const int*   mask  = (const int*)d_in[6];     // [4,1,1024,2048]
    float* out = (float*)d_out;

    char* ws = (char*)d_ws;
    short* q_bf   = (short*)ws; ws += (size_t)4096 * 768 * 2;
    short* kv_bf  = (short*)ws; ws += (size_t)8192 * 768 * 2;
    short* Wq_bf  = (short*)ws; ws += (size_t)768 * 768 * 2;
    short* Wkv_bf = (short*)ws; ws += (size_t)1536 * 768 * 2;
    short* Wp_bf  = (short*)ws; ws += (size_t)768 * 768 * 2;
    short* qp     = (short*)ws; ws += (size_t)4096 * 768 * 2;   // [B,H,N,64]
    short* kk     = (short*)ws; ws += (size_t)8192 * 768 * 2;   // [B,H,M,64]
    short* vt     = (short*)ws; ws += (size_t)8192 * 768 * 2;   // [B,H,64,M]
    short* xb     = (short*)ws; ws += (size_t)4096 * 768 * 2;   // [B,N,768]
    unsigned* mbits = (unsigned*)ws;                            // [B,N,64]

    cast_f2b_kernel<<<1536, 256, 0, stream>>>(q, q_bf, 4096 * 768);
    cast_f2b_kernel<<<3072, 256, 0, stream>>>(kv, kv_bf, 8192 * 768);
    cast_f2b_kernel<<<288, 256, 0, stream>>>(Wq, Wq_bf, 768 * 768);
    cast_f2b_kernel<<<576, 256, 0, stream>>>(Wkv, Wkv_bf, 1536 * 768);
    cast_f2b_kernel<<<288, 256, 0, stream>>>(Wproj, Wp_bf, 768 * 768);
    pack_mask_kernel<<<32768, 256, 0, stream>>>(mask, mbits);

    // qp = (q @ Wq^T) * scale, scattered per-head
    gemm_bt_kernel<<<(4096 / 128) * (768 / 128), 256, 0, stream>>>(
        q_bf, Wq_bf, 768, 0, nullptr, qp, nullptr, nullptr);
    // kv proj -> K and V^T
    gemm_bt_kernel<<<(8192 / 128) * (1536 / 128), 256, 0, stream>>>(
        kv_bf, Wkv_bf, 1536, 1, nullptr, kk, vt, nullptr);
    // attention
    attn_kernel<<<BB * NUM_H * (NQ / 64), 256, 0, stream>>>(qp, kk, vt, mbits, xb);
    // out = x @ Wproj^T + bproj
    gemm_bt_kernel<<<(4096 / 128) * (768 / 128), 256, 0, stream>>>(
        xb, Wp_bf, 768, 2, bproj, nullptr, nullptr, out);
}

// Round 2
// 256.754 us; speedup vs baseline: 1.8914x; 1.8914x over previous
//
#include <hip/hip_runtime.h>
#include <hip/hip_bf16.h>

// ---------------------------------------------------------------------------
// Attention_CA: out = Proj( Softmax(mask, scale * (q Wq^T) (kv Wkv^T)_K^T) (kv Wkv^T)_V )
// B=4, N=1024, M=2048, C=768, H=12, d=64.  bf16 MFMA pipeline, fp32 accum.
// Round 2: coalesced epilogues (LDS round-trip), fixed-max exp2 softmax with
// MFMA row-sum, software prefetch in gemm+attn.
// ---------------------------------------------------------------------------

typedef short  s16x8  __attribute__((ext_vector_type(8)));
typedef short  s16x4  __attribute__((ext_vector_type(4)));
typedef __bf16 bf16x8 __attribute__((ext_vector_type(8)));
typedef float  f32x4  __attribute__((ext_vector_type(4)));

#define NUM_H 12
#define DIM   768
#define BB    4
#define NQ    1024
#define MK    2048
// scale * log2(e): softmax computed with exp2 (v_exp_f32), base cancels in norm
#define QK_SCALE_LOG2E 0.18033688f

__device__ __forceinline__ short f2b(float v) {
    __hip_bfloat16 h = __float2bfloat16(v);   // RNE
    return __builtin_bit_cast(short, h);
}

__device__ __forceinline__ f32x4 mfma16(bf16x8 a, bf16x8 b, f32x4 c) {
    return __builtin_amdgcn_mfma_f32_16x16x32_bf16(a, b, c, 0, 0, 0);
}

// ---------------------------- cast fp32 -> bf16 ----------------------------
__global__ __launch_bounds__(256) void cast_f2b_kernel(
    const float* __restrict__ s, short* __restrict__ d, int n)
{
    int i = (blockIdx.x * 256 + threadIdx.x) * 8;
    if (i >= n) return;
    float4 a = *(const float4*)(s + i);
    float4 b = *(const float4*)(s + i + 4);
    s16x8 r;
    r[0] = f2b(a.x); r[1] = f2b(a.y); r[2] = f2b(a.z); r[3] = f2b(a.w);
    r[4] = f2b(b.x); r[5] = f2b(b.y); r[6] = f2b(b.z); r[7] = f2b(b.w);
    *(s16x8*)(d + i) = r;
}

// ---------------------------- pack mask to bits ----------------------------
__global__ __launch_bounds__(256) void pack_mask_kernel(
    const int* __restrict__ m, unsigned* __restrict__ mb)
{
    int i = blockIdx.x * 256 + threadIdx.x;
    unsigned long long bal = __ballot(m[i] != 0);
    if ((threadIdx.x & 63) == 0) {
        int wi = i >> 5;
        mb[wi]     = (unsigned)bal;
        mb[wi + 1] = (unsigned)(bal >> 32);
    }
}

// ---------------------------- GEMM: C = A @ Bt^T ---------------------------
// A [Mrows,768] bf16 row-major, Bt [Ncols,768] bf16 row-major.
// 128x128 tile, BK=64, 4 waves, prefetched staging.
// mode 0: qp scatter [B,H,N,d] bf16, *QK_SCALE_LOG2E   (coalesced via LDS)
// mode 1: kv split -> K [B,H,M,d] bf16, V^T [B,H,d,M] bf16 (LDS transpose)
// mode 2: out fp32 = v + bias[col] (direct, 64B runs)
__global__ __launch_bounds__(256) void gemm_bt_kernel(
    const short* __restrict__ A, const short* __restrict__ Bt,
    int Ncols, int mode, const float* __restrict__ bias,
    short* __restrict__ outb, short* __restrict__ outb2,
    float* __restrict__ outf)
{
    __shared__ short smem[18432];                    // 36.9 KB
    short (*As)[72] = (short(*)[72])smem;
    short (*Bs)[72] = (short(*)[72])(smem + 9216);

    int ntiles = Ncols >> 7;
    int m0 = (blockIdx.x / ntiles) << 7;
    int n0 = (blockIdx.x % ntiles) << 7;
    int t = threadIdx.x;
    int w = t >> 6, lane = t & 63, quad = lane >> 4, l16 = lane & 15;
    int wm = (w & 1) << 6, wn = (w >> 1) << 6;

    f32x4 zero4 = {0.f, 0.f, 0.f, 0.f};
    f32x4 acc[4][4];
    for (int i = 0; i < 4; i++)
        for (int j = 0; j < 4; j++) acc[i][j] = zero4;

    int lr = t >> 1;            // 0..127
    int lc = (t & 1) << 5;      // 0 or 32
    const short* Ap = A + (long)(m0 + lr) * DIM + lc;
    const short* Bp = Bt + (long)(n0 + lr) * DIM + lc;

    s16x8 a8[4], b8[4];
    #pragma unroll
    for (int c = 0; c < 4; c++) {
        a8[c] = *(const s16x8*)(Ap + c * 8);
        b8[c] = *(const s16x8*)(Bp + c * 8);
    }

    for (int kt = 0; kt < DIM; kt += 64) {
        __syncthreads();
        #pragma unroll
        for (int c = 0; c < 4; c++) {
            *(s16x8*)&As[lr][lc + c * 8] = a8[c];
            *(s16x8*)&Bs[lr][lc + c * 8] = b8[c];
        }
        __syncthreads();
        if (kt + 64 < DIM) {
            #pragma unroll
            for (int c = 0; c < 4; c++) {
                a8[c] = *(const s16x8*)(Ap + kt + 64 + c * 8);
                b8[c] = *(const s16x8*)(Bp + kt + 64 + c * 8);
            }
        }
        #pragma unroll
        for (int kh = 0; kh < 2; kh++) {
            bf16x8 af[4], bfr[4];
            #pragma unroll
            for (int i = 0; i < 4; i++) {
                s16x8 tmp = *(const s16x8*)&As[wm + i * 16 + l16][kh * 32 + quad * 8];
                af[i] = __builtin_bit_cast(bf16x8, tmp);
            }
            #pragma unroll
            for (int j = 0; j < 4; j++) {
                s16x8 tmp = *(const s16x8*)&Bs[wn + j * 16 + l16][kh * 32 + quad * 8];
                bfr[j] = __builtin_bit_cast(bf16x8, tmp);
            }
            #pragma unroll
            for (int i = 0; i < 4; i++)
                #pragma unroll
                for (int j = 0; j < 4; j++)
                    acc[i][j] = mfma16(af[i], bfr[j], acc[i][j]);
        }
    }

    __syncthreads();   // all MFMA LDS reads done; smem reusable

    if (mode == 2) {
        #pragma unroll
        for (int i = 0; i < 4; i++)
            #pragma unroll
            for (int j = 0; j < 4; j++)
                #pragma unroll
                for (int r = 0; r < 4; r++) {
                    int row = m0 + wm + i * 16 + quad * 4 + r;
                    int col = n0 + wn + j * 16 + l16;
                    outf[(long)row * DIM + col] = acc[i][j][r] + bias[col];
                }
        return;
    }

    short (*Cs)[136] = (short(*)[136])smem;          // 128x136 bf16 = 34.8 KB
    bool vreg = (mode == 1) && (n0 >= DIM);

    if (!vreg) {
        float sc = (mode == 0) ? QK_SCALE_LOG2E : 1.0f;
        #pragma unroll
        for (int i = 0; i < 4; i++)
            #pragma unroll
            for (int j = 0; j < 4; j++)
                #pragma unroll
                for (int r = 0; r < 4; r++)
                    Cs[wm + i * 16 + quad * 4 + r][wn + j * 16 + l16] =
                        f2b(acc[i][j][r] * sc);
    } else {
        #pragma unroll
        for (int i = 0; i < 4; i++)
            #pragma unroll
            for (int j = 0; j < 4; j++) {
                int c = wn + j * 16 + l16;
                int r0 = wm + i * 16 + quad * 4;
                s16x4 pk;
                pk[0] = f2b(acc[i][j][0]); pk[1] = f2b(acc[i][j][1]);
                pk[2] = f2b(acc[i][j][2]); pk[3] = f2b(acc[i][j][3]);
                *(s16x4*)&Cs[c][r0] = pk;            // transposed: Cs[dd][m]
            }
    }
    __syncthreads();

    if (!vreg) {
        // output region per head-half: 128 rows x 64 dd, fully contiguous 16 KB
        int hb2 = n0 >> 6;
        long rowsN = (mode == 0) ? NQ : MK;
        int b = (int)(m0 / rowsN);
        int rb = (int)(m0 % rowsN);
        short* ob0 = outb + ((long)(b * NUM_H + hb2) * rowsN + rb) * 64;
        short* ob1 = outb + ((long)(b * NUM_H + hb2 + 1) * rowsN + rb) * 64;
        #pragma unroll
        for (int k2 = 0; k2 < 8; k2++) {
            int ch = k2 * 256 + t;
            int half = ch >> 10, off = ch & 1023;
            s16x8 vd = *(const s16x8*)&Cs[off >> 3][(half << 6) + ((off & 7) << 3)];
            *(s16x8*)((half ? ob1 : ob0) + off * 8) = vd;
        }
    } else {
        // V^T: per dd, 128 m-values contiguous (256 B runs)
        int hb2 = (n0 - DIM) >> 6;
        int b = m0 >> 11, rb = m0 & 2047;
        #pragma unroll
        for (int k2 = 0; k2 < 8; k2++) {
            int ch = k2 * 256 + t;
            int c = ch >> 4, woff = (ch & 15) << 3;
            s16x8 vd = *(const s16x8*)&Cs[c][woff];
            int half = c >> 6, dd = c & 63;
            *(s16x8*)(outb2 + (((long)(b * NUM_H + hb2 + half) * 64 + dd) * MK + rb) + woff) = vd;
        }
    }
}

// ------------------------- flash attention (bf16 MFMA) ---------------------
// Fixed-max softmax: p = mask ? exp2(s') : 0 (s' pre-scaled by scale*log2e).
// Row-sum l via MFMA with ones-fragment. Prefetched K/V staging.
__global__ __launch_bounds__(256) void attn_kernel(
    const short* __restrict__ qp, const short* __restrict__ kk,
    const short* __restrict__ vt, const unsigned* __restrict__ mb,
    short* __restrict__ xb)
{
    __shared__ short qs[64][72];
    __shared__ short ks[64][72];
    __shared__ short vs[64][72];       // V^T tile: [dd][m]
    __shared__ short ps[4][16][72];    // per-wave P / O staging
    __shared__ unsigned mw[64][2];

    int bid = blockIdx.x;
    int nt = bid & 15;
    int bh = bid >> 4;
    int h = bh % NUM_H, b = bh / NUM_H;
    int n0 = nt << 6;
    int t = threadIdx.x, w = t >> 6, lane = t & 63, quad = lane >> 4, l16 = lane & 15;

    const short* qbase = qp + ((long)bh * NQ + n0) * 64;
    const short* kbase = kk + (long)bh * MK * 64;
    const short* vbase = vt + (long)bh * 64 * MK;
    const unsigned* mbase = mb + ((long)b * NQ + n0) * 64;

    {   // stage Q tile once
        int qr = t >> 2, c0 = (t & 3) << 4;
        *(s16x8*)&qs[qr][c0]     = *(const s16x8*)(qbase + qr * 64 + c0);
        *(s16x8*)&qs[qr][c0 + 8] = *(const s16x8*)(qbase + qr * 64 + c0 + 8);
    }
    __syncthreads();
    bf16x8 aq[2];
    {
        s16x8 t0 = *(const s16x8*)&qs[(w << 4) + l16][quad * 8];
        s16x8 t1 = *(const s16x8*)&qs[(w << 4) + l16][32 + quad * 8];
        aq[0] = __builtin_bit_cast(bf16x8, t0);
        aq[1] = __builtin_bit_cast(bf16x8, t1);
    }

    int sr = t >> 2, c0 = (t & 3) << 4;
    const short* kp = kbase + (long)sr * 64 + c0;
    const short* vp = vbase + (long)sr * MK + c0;

    s16x8 k0 = *(const s16x8*)(kp);
    s16x8 k1 = *(const s16x8*)(kp + 8);
    s16x8 v0 = *(const s16x8*)(vp);
    s16x8 v1 = *(const s16x8*)(vp + 8);
    unsigned mword = (t < 128) ? mbase[(t >> 1) * 64 + (t & 1)] : 0u;

    f32x4 zero4 = {0.f, 0.f, 0.f, 0.f};
    f32x4 o[4], ol = zero4;
    for (int j = 0; j < 4; j++) o[j] = zero4;

    s16x8 ones8 = {0x3F80, 0x3F80, 0x3F80, 0x3F80, 0x3F80, 0x3F80, 0x3F80, 0x3F80};
    bf16x8 ones = __builtin_bit_cast(bf16x8, ones8);

    for (int mt = 0; mt < MK; mt += 64) {
        __syncthreads();                       // prev compute done with ks/vs
        *(s16x8*)&ks[sr][c0]     = k0;
        *(s16x8*)&ks[sr][c0 + 8] = k1;
        *(s16x8*)&vs[sr][c0]     = v0;
        *(s16x8*)&vs[sr][c0 + 8] = v1;
        if (t < 128) mw[t >> 1][t & 1] = mword;
        __syncthreads();
        if (mt + 64 < MK) {                    // prefetch next tile
            k0 = *(const s16x8*)(kp + (long)(mt + 64) * 64);
            k1 = *(const s16x8*)(kp + (long)(mt + 64) * 64 + 8);
            v0 = *(const s16x8*)(vp + mt + 64);
            v1 = *(const s16x8*)(vp + mt + 64 + 8);
            if (t < 128) mword = mbase[(t >> 1) * 64 + ((mt + 64) >> 5) + (t & 1)];
        }

        // S = Q K^T (16 q-rows x 64 m-cols per wave), pre-scaled for exp2
        f32x4 s[4];
        for (int j = 0; j < 4; j++) s[j] = zero4;
        #pragma unroll
        for (int kh = 0; kh < 2; kh++)
            #pragma unroll
            for (int j = 0; j < 4; j++) {
                s16x8 tk = *(const s16x8*)&ks[j * 16 + l16][kh * 32 + quad * 8];
                s[j] = mfma16(aq[kh], __builtin_bit_cast(bf16x8, tk), s[j]);
            }

        // p = mask ? exp2(s) : 0; store to wave-private ps (A-layout)
        #pragma unroll
        for (int rr = 0; rr < 4; rr++) {
            int qrow = (w << 4) + quad * 4 + rr;
            unsigned w0 = mw[qrow][0], w1 = mw[qrow][1];
            float e0 = __builtin_amdgcn_exp2f(s[0][rr]);
            float e1 = __builtin_amdgcn_exp2f(s[1][rr]);
            float e2 = __builtin_amdgcn_exp2f(s[2][rr]);
            float e3 = __builtin_amdgcn_exp2f(s[3][rr]);
            short p0 = ((w0 >> l16) & 1)        ? f2b(e0) : (short)0;
            short p1 = ((w0 >> (16 + l16)) & 1) ? f2b(e1) : (short)0;
            short p2 = ((w1 >> l16) & 1)        ? f2b(e2) : (short)0;
            short p3 = ((w1 >> (16 + l16)) & 1) ? f2b(e3) : (short)0;
            ps[w][quad * 4 + rr][l16]      = p0;
            ps[w][quad * 4 + rr][16 + l16] = p1;
            ps[w][quad * 4 + rr][32 + l16] = p2;
            ps[w][quad * 4 + rr][48 + l16] = p3;
        }

        // O += P @ V ; l += P @ ones   (ps is wave-private: no barrier needed)
        #pragma unroll
        for (int kh = 0; kh < 2; kh++) {
            s16x8 tp = *(const s16x8*)&ps[w][l16][kh * 32 + quad * 8];
            bf16x8 ap = __builtin_bit_cast(bf16x8, tp);
            ol = mfma16(ap, ones, ol);
            #pragma unroll
            for (int jd = 0; jd < 4; jd++) {
                s16x8 tv = *(const s16x8*)&vs[jd * 16 + l16][kh * 32 + quad * 8];
                o[jd] = mfma16(ap, __builtin_bit_cast(bf16x8, tv), o[jd]);
            }
        }
    }

    // epilogue: normalize, round-trip via wave-private ps, coalesced store
    float linv[4];
    #pragma unroll
    for (int rr = 0; rr < 4; rr++) linv[rr] = 1.0f / ol[rr];
    #pragma unroll
    for (int jd = 0; jd < 4; jd++)
        #pragma unroll
        for (int rr = 0; rr < 4; rr++)
            ps[w][quad * 4 + rr][jd * 16 + l16] = f2b(o[jd][rr] * linv[rr]);

    #pragma unroll
    for (int k2 = 0; k2 < 2; k2++) {
        int row = (lane >> 3) + k2 * 8;
        int cc = (lane & 7) << 3;
        s16x8 vd = *(const s16x8*)&ps[w][row][cc];
        *(s16x8*)(xb + ((long)b * NQ + n0 + (w << 4) + row) * DIM + h * 64 + cc) = vd;
    }
}

// ---------------------------------------------------------------------------
extern "C" void kernel_launch(void* const* d_in, const int* in_sizes, int n_in,
                              void* d_out, int out_size, void* d_ws, size_t ws_size,
                              hipStream_t stream)
{
    const float* q     = (const float*)d_in[0];
    const float* kv    = (const float*)d_in[1];
    const float* Wq    = (const float*)d_in[2];
    const float* Wkv   = (const float*)d_in[3];
    const float* Wproj = (const float*)d_in[4];
    const float* bproj = (const float*)d_in[5];
    const int*   mask  = (const int*)d_in[6];
    float* out = (float*)d_out;

    char* ws = (char*)d_ws;
    short* q_bf   = (short*)ws; ws += (size_t)4096 * 768 * 2;
    short* kv_bf  = (short*)ws; ws += (size_t)8192 * 768 * 2;
    short* Wq_bf  = (short*)ws; ws += (size_t)768 * 768 * 2;
    short* Wkv_bf = (short*)ws; ws += (size_t)1536 * 768 * 2;
    short* Wp_bf  = (short*)ws; ws += (size_t)768 * 768 * 2;
    short* qp     = (short*)ws; ws += (size_t)4096 * 768 * 2;   // [B,H,N,64]
    short* kk     = (short*)ws; ws += (size_t)8192 * 768 * 2;   // [B,H,M,64]
    short* vt     = (short*)ws; ws += (size_t)8192 * 768 * 2;   // [B,H,64,M]
    short* xb     = (short*)ws; ws += (size_t)4096 * 768 * 2;   // [B,N,768]
    unsigned* mbits = (unsigned*)ws;                            // [B,N,64]

    cast_f2b_kernel<<<1536, 256, 0, stream>>>(q, q_bf, 4096 * 768);
    cast_f2b_kernel<<<3072, 256, 0, stream>>>(kv, kv_bf, 8192 * 768);
    cast_f2b_kernel<<<288, 256, 0, stream>>>(Wq, Wq_bf, 768 * 768);
    cast_f2b_kernel<<<576, 256, 0, stream>>>(Wkv, Wkv_bf, 1536 * 768);
    cast_f2b_kernel<<<288, 256, 0, stream>>>(Wproj, Wp_bf, 768 * 768);
    pack_mask_kernel<<<32768, 256, 0, stream>>>(mask, mbits);

    gemm_bt_kernel<<<(4096 / 128) * (768 / 128), 256, 0, stream>>>(
        q_bf, Wq_bf, 768, 0, nullptr, qp, nullptr, nullptr);
    gemm_bt_kernel<<<(8192 / 128) * (1536 / 128), 256, 0, stream>>>(
        kv_bf, Wkv_bf, 1536, 1, nullptr, kk, vt, nullptr);
    attn_kernel<<<BB * NUM_H * (NQ / 64), 256, 0, stream>>>(qp, kk, vt, mbits, xb);
    gemm_bt_kernel<<<(4096 / 128) * (768 / 128), 256, 0, stream>>>(
        xb, Wp_bf, 768, 2, bproj, nullptr, nullptr, out);
}

// Round 4
// 221.697 us; speedup vs baseline: 2.1905x; 1.1581x over previous
//
#include <hip/hip_runtime.h>
#include <hip/hip_bf16.h>

// ---------------------------------------------------------------------------
// Attention_CA: out = Proj( Softmax(mask, scale * (q Wq^T) (kv Wkv^T)_K^T) (kv Wkv^T)_V )
// B=4, N=1024, M=2048, C=768, H=12, d=64.
// Round 4 (= R3 + compile fix): S^T orientation -> P stays in registers
// (K=16 fp16 PV MFMA), per-lane mask from global, fused prep kernel,
// fused qp+kv gemm launch, XCD-aware head swizzle in attention.
// ---------------------------------------------------------------------------

typedef short    s16x8  __attribute__((ext_vector_type(8)));
typedef short    s16x4  __attribute__((ext_vector_type(4)));
typedef __bf16   bf16x8 __attribute__((ext_vector_type(8)));
typedef float    f32x4  __attribute__((ext_vector_type(4)));
typedef _Float16 f16x4  __attribute__((ext_vector_type(4)));
typedef _Float16 f16x2  __attribute__((ext_vector_type(2)));

#define NUM_H 12
#define DIM   768
#define NQ    1024
#define MK    2048
// scale * log2(e): softmax via exp2, base cancels in normalization
#define QK_SCALE_LOG2E 0.18033688f

__device__ __forceinline__ short f2b(float v) {
    __hip_bfloat16 h = __float2bfloat16(v);   // RNE
    return __builtin_bit_cast(short, h);
}
__device__ __forceinline__ short f2h(float v) {
    _Float16 h = (_Float16)v;                 // RNE, single v_cvt_f16_f32
    return __builtin_bit_cast(short, h);
}
__device__ __forceinline__ f32x4 mfma_bf16_k32(bf16x8 a, bf16x8 b, f32x4 c) {
    return __builtin_amdgcn_mfma_f32_16x16x32_bf16(a, b, c, 0, 0, 0);
}
__device__ __forceinline__ f32x4 mfma_f16_k16(f16x4 a, f16x4 b, f32x4 c) {
    return __builtin_amdgcn_mfma_f32_16x16x16f16(a, b, c, 0, 0, 0);
}
__device__ __forceinline__ f16x2 pk2h(float a, float b) {
    return __builtin_bit_cast(f16x2, __builtin_amdgcn_cvt_pkrtz(a, b));
}

// ------------------- prep: all casts + mask byte-pack ----------------------
// blocks [0,5760): fp32->bf16 casts (2048 elems/block)
// blocks [5760,9856): mask int32 -> bit-per-element bytes (2048 ints/block)
__global__ __launch_bounds__(256) void prep_kernel(
    const float* __restrict__ q, const float* __restrict__ kv,
    const float* __restrict__ Wq, const float* __restrict__ Wkv,
    const float* __restrict__ Wp, const int* __restrict__ mask,
    short* __restrict__ q_bf, short* __restrict__ kv_bf,
    short* __restrict__ Wq_bf, short* __restrict__ Wkv_bf,
    short* __restrict__ Wp_bf, unsigned char* __restrict__ mbytes)
{
    int bid = blockIdx.x;
    if (bid < 5760) {
        const float* s; short* d; long base;
        if (bid < 1536)      { s = q;   d = q_bf;   base = (long)bid * 2048; }
        else if (bid < 4608) { s = kv;  d = kv_bf;  base = (long)(bid - 1536) * 2048; }
        else if (bid < 4896) { s = Wq;  d = Wq_bf;  base = (long)(bid - 4608) * 2048; }
        else if (bid < 5472) { s = Wkv; d = Wkv_bf; base = (long)(bid - 4896) * 2048; }
        else                 { s = Wp;  d = Wp_bf;  base = (long)(bid - 5472) * 2048; }
        long i = base + threadIdx.x * 8;
        float4 a = *(const float4*)(s + i);
        float4 b = *(const float4*)(s + i + 4);
        s16x8 r;
        r[0] = f2b(a.x); r[1] = f2b(a.y); r[2] = f2b(a.z); r[3] = f2b(a.w);
        r[4] = f2b(b.x); r[5] = f2b(b.y); r[6] = f2b(b.z); r[7] = f2b(b.w);
        *(s16x8*)(d + i) = r;
    } else {
        long base = (long)(bid - 5760) * 2048 + threadIdx.x * 8;
        int4 m0 = *(const int4*)(mask + base);
        int4 m1 = *(const int4*)(mask + base + 4);
        unsigned v = (unsigned)(m0.x != 0)        | ((unsigned)(m0.y != 0) << 1)
                   | ((unsigned)(m0.z != 0) << 2) | ((unsigned)(m0.w != 0) << 3)
                   | ((unsigned)(m1.x != 0) << 4) | ((unsigned)(m1.y != 0) << 5)
                   | ((unsigned)(m1.z != 0) << 6) | ((unsigned)(m1.w != 0) << 7);
        mbytes[base >> 3] = (unsigned char)v;
    }
}

// ---------------------------- GEMM core: C = A @ Bt^T ----------------------
// mode 0: qp scatter [B,H,N,d] bf16, *QK_SCALE_LOG2E
// mode 1: kv split -> K [B,H,M,d] bf16, V^T [B,H,d,M] fp16
// mode 2: out fp32 = v + bias[col]
__device__ __forceinline__ void gemm_core(
    short* smem,
    const short* __restrict__ A, const short* __restrict__ Bt,
    int Ncols, int mode, const float* __restrict__ bias,
    short* __restrict__ outb, short* __restrict__ outb2,
    float* __restrict__ outf, int bid)
{
    short (*As)[72] = (short(*)[72])smem;
    short (*Bs)[72] = (short(*)[72])(smem + 9216);

    int ntiles = Ncols >> 7;
    int m0 = (bid / ntiles) << 7;
    int n0 = (bid % ntiles) << 7;
    int t = threadIdx.x;
    int w = t >> 6, lane = t & 63, quad = lane >> 4, l16 = lane & 15;
    int wm = (w & 1) << 6, wn = (w >> 1) << 6;

    f32x4 zero4 = {0.f, 0.f, 0.f, 0.f};
    f32x4 acc[4][4];
    for (int i = 0; i < 4; i++)
        for (int j = 0; j < 4; j++) acc[i][j] = zero4;

    int lr = t >> 1;
    int lc = (t & 1) << 5;
    const short* Ap = A + (long)(m0 + lr) * DIM + lc;
    const short* Bp = Bt + (long)(n0 + lr) * DIM + lc;

    s16x8 a8[4], b8[4];
    #pragma unroll
    for (int c = 0; c < 4; c++) {
        a8[c] = *(const s16x8*)(Ap + c * 8);
        b8[c] = *(const s16x8*)(Bp + c * 8);
    }

    for (int kt = 0; kt < DIM; kt += 64) {
        __syncthreads();
        #pragma unroll
        for (int c = 0; c < 4; c++) {
            *(s16x8*)&As[lr][lc + c * 8] = a8[c];
            *(s16x8*)&Bs[lr][lc + c * 8] = b8[c];
        }
        __syncthreads();
        if (kt + 64 < DIM) {
            #pragma unroll
            for (int c = 0; c < 4; c++) {
                a8[c] = *(const s16x8*)(Ap + kt + 64 + c * 8);
                b8[c] = *(const s16x8*)(Bp + kt + 64 + c * 8);
            }
        }
        #pragma unroll
        for (int kh = 0; kh < 2; kh++) {
            bf16x8 af[4], bfr[4];
            #pragma unroll
            for (int i = 0; i < 4; i++) {
                s16x8 tmp = *(const s16x8*)&As[wm + i * 16 + l16][kh * 32 + quad * 8];
                af[i] = __builtin_bit_cast(bf16x8, tmp);
            }
            #pragma unroll
            for (int j = 0; j < 4; j++) {
                s16x8 tmp = *(const s16x8*)&Bs[wn + j * 16 + l16][kh * 32 + quad * 8];
                bfr[j] = __builtin_bit_cast(bf16x8, tmp);
            }
            #pragma unroll
            for (int i = 0; i < 4; i++)
                #pragma unroll
                for (int j = 0; j < 4; j++)
                    acc[i][j] = mfma_bf16_k32(af[i], bfr[j], acc[i][j]);
        }
    }

    __syncthreads();   // MFMA LDS reads done; smem reusable

    if (mode == 2) {
        #pragma unroll
        for (int i = 0; i < 4; i++)
            #pragma unroll
            for (int j = 0; j < 4; j++)
                #pragma unroll
                for (int r = 0; r < 4; r++) {
                    int row = m0 + wm + i * 16 + quad * 4 + r;
                    int col = n0 + wn + j * 16 + l16;
                    outf[(long)row * DIM + col] = acc[i][j][r] + bias[col];
                }
        return;
    }

    short (*Cs)[136] = (short(*)[136])smem;
    bool vreg = (mode == 1) && (n0 >= DIM);

    if (!vreg) {
        float sc = (mode == 0) ? QK_SCALE_LOG2E : 1.0f;
        #pragma unroll
        for (int i = 0; i < 4; i++)
            #pragma unroll
            for (int j = 0; j < 4; j++)
                #pragma unroll
                for (int r = 0; r < 4; r++)
                    Cs[wm + i * 16 + quad * 4 + r][wn + j * 16 + l16] =
                        f2b(acc[i][j][r] * sc);
    } else {
        #pragma unroll
        for (int i = 0; i < 4; i++)
            #pragma unroll
            for (int j = 0; j < 4; j++) {
                int c = wn + j * 16 + l16;
                int r0 = wm + i * 16 + quad * 4;
                s16x4 pk;
                pk[0] = f2h(acc[i][j][0]); pk[1] = f2h(acc[i][j][1]);
                pk[2] = f2h(acc[i][j][2]); pk[3] = f2h(acc[i][j][3]);
                *(s16x4*)&Cs[c][r0] = pk;            // transposed: Cs[dd][m], fp16
            }
    }
    __syncthreads();

    if (!vreg) {
        int hb2 = n0 >> 6;
        long rowsN = (mode == 0) ? NQ : MK;
        int b = (int)(m0 / rowsN);
        int rb = (int)(m0 % rowsN);
        short* ob0 = outb + ((long)(b * NUM_H + hb2) * rowsN + rb) * 64;
        short* ob1 = outb + ((long)(b * NUM_H + hb2 + 1) * rowsN + rb) * 64;
        #pragma unroll
        for (int k2 = 0; k2 < 8; k2++) {
            int ch = k2 * 256 + t;
            int half = ch >> 10, off = ch & 1023;
            s16x8 vd = *(const s16x8*)&Cs[off >> 3][(half << 6) + ((off & 7) << 3)];
            *(s16x8*)((half ? ob1 : ob0) + off * 8) = vd;
        }
    } else {
        int hb2 = (n0 - DIM) >> 6;
        int b = m0 >> 11, rb = m0 & 2047;
        #pragma unroll
        for (int k2 = 0; k2 < 8; k2++) {
            int ch = k2 * 256 + t;
            int c = ch >> 4, woff = (ch & 15) << 3;
            s16x8 vd = *(const s16x8*)&Cs[c][woff];
            int half = c >> 6, dd = c & 63;
            *(s16x8*)(outb2 + (((long)(b * NUM_H + hb2 + half) * 64 + dd) * MK + rb) + woff) = vd;
        }
    }
}

__global__ __launch_bounds__(256) void gemm12_kernel(
    const short* __restrict__ qbf, const short* __restrict__ Wqbf,
    const short* __restrict__ kvbf, const short* __restrict__ Wkvbf,
    short* __restrict__ qp, short* __restrict__ kk, short* __restrict__ vt)
{
    __shared__ short smem[18432];
    if (blockIdx.x < 192)
        gemm_core(smem, qbf, Wqbf, 768, 0, nullptr, qp, nullptr, nullptr, blockIdx.x);
    else
        gemm_core(smem, kvbf, Wkvbf, 1536, 1, nullptr, kk, vt, nullptr, blockIdx.x - 192);
}

__global__ __launch_bounds__(256) void gemm3_kernel(
    const short* __restrict__ xb, const short* __restrict__ Wpbf,
    const float* __restrict__ bias, float* __restrict__ out)
{
    __shared__ short smem[18432];
    gemm_core(smem, xb, Wpbf, 768, 2, bias, nullptr, nullptr, out, blockIdx.x);
}

// ------------------------- flash attention ---------------------------------
// S^T = K Q^T via bf16 K=32 MFMA: lane l16 = q-row, regs = m-cols (quad*4+rr).
// That register layout IS the fp16 K=16 A-fragment -> PV with no LDS transit.
// Mask bits per-lane from global. ones-MFMA row-sum. qs reused for epilogue.
__global__ __launch_bounds__(256) void attn_kernel(
    const short* __restrict__ qp, const short* __restrict__ kk,
    const short* __restrict__ vt, const unsigned* __restrict__ mb,
    short* __restrict__ xb)
{
    __shared__ short qs[64][72];       // Q tile; reused as O staging in epilogue
    __shared__ short ks[64][72];       // K tile  [m][d]   bf16
    __shared__ short vs[64][72];       // V^T tile [dd][m] fp16

    int bid = blockIdx.x;
    int bh = bid % 48;                 // XCD swizzle: head bh -> XCD bh%8
    int nt = bid / 48;
    int h = bh % NUM_H, b = bh / NUM_H;
    int n0 = nt << 6;
    int t = threadIdx.x, w = t >> 6, lane = t & 63, quad = lane >> 4, l16 = lane & 15;

    const short* qbase = qp + ((long)bh * NQ + n0) * 64;
    const short* kbase = kk + (long)bh * MK * 64;
    const short* vbase = vt + (long)bh * 64 * MK;
    const unsigned* mrow = mb + ((long)b * NQ + n0 + (w << 4) + l16) * 64;

    {   // stage Q tile once
        int qr = t >> 2, c0 = (t & 3) << 4;
        *(s16x8*)&qs[qr][c0]     = *(const s16x8*)(qbase + qr * 64 + c0);
        *(s16x8*)&qs[qr][c0 + 8] = *(const s16x8*)(qbase + qr * 64 + c0 + 8);
    }
    __syncthreads();
    bf16x8 bq[2];                      // B-fragment: rows = this wave's q-rows
    {
        s16x8 t0 = *(const s16x8*)&qs[(w << 4) + l16][quad * 8];
        s16x8 t1 = *(const s16x8*)&qs[(w << 4) + l16][32 + quad * 8];
        bq[0] = __builtin_bit_cast(bf16x8, t0);
        bq[1] = __builtin_bit_cast(bf16x8, t1);
    }

    int sr = t >> 2, c0 = (t & 3) << 4;
    const short* kp = kbase + (long)sr * 64 + c0;
    const short* vp = vbase + (long)sr * MK + c0;

    s16x8 k0 = *(const s16x8*)(kp);
    s16x8 k1 = *(const s16x8*)(kp + 8);
    s16x8 v0 = *(const s16x8*)(vp);
    s16x8 v1 = *(const s16x8*)(vp + 8);
    uint2 mwv = *(const uint2*)(mrow);

    f32x4 zero4 = {0.f, 0.f, 0.f, 0.f};
    f32x4 o[4], ol = zero4;
    for (int j = 0; j < 4; j++) o[j] = zero4;
    const f16x4 ones = {(_Float16)1.f, (_Float16)1.f, (_Float16)1.f, (_Float16)1.f};

    for (int mt = 0; mt < MK; mt += 64) {
        __syncthreads();
        *(s16x8*)&ks[sr][c0]     = k0;
        *(s16x8*)&ks[sr][c0 + 8] = k1;
        *(s16x8*)&vs[sr][c0]     = v0;
        *(s16x8*)&vs[sr][c0 + 8] = v1;
        unsigned cm0 = mwv.x, cm1 = mwv.y;      // save BEFORE prefetch clobbers
        __syncthreads();
        if (mt + 64 < MK) {
            k0 = *(const s16x8*)(kp + (long)(mt + 64) * 64);
            k1 = *(const s16x8*)(kp + (long)(mt + 64) * 64 + 8);
            v0 = *(const s16x8*)(vp + mt + 64);
            v1 = *(const s16x8*)(vp + mt + 64 + 8);
            mwv = *(const uint2*)(mrow + ((mt + 64) >> 5));
        }

        // S^T = K Q^T : s[j][rr] = S[qrow=l16][m = j*16 + quad*4 + rr]
        f32x4 s[4];
        for (int j = 0; j < 4; j++) s[j] = zero4;
        #pragma unroll
        for (int kh = 0; kh < 2; kh++)
            #pragma unroll
            for (int j = 0; j < 4; j++) {
                s16x8 tk = *(const s16x8*)&ks[j * 16 + l16][kh * 32 + quad * 8];
                s[j] = mfma_bf16_k32(__builtin_bit_cast(bf16x8, tk), bq[kh], s[j]);
            }

        // p = mask ? exp2(s) : 0, packed to fp16 A-fragments (in-register)
        f16x4 pa[4];
        #pragma unroll
        for (int j = 0; j < 4; j++) {
            unsigned wsel = (j < 2) ? cm0 : cm1;
            unsigned bits = wsel >> (((j & 1) << 4) + (quad << 2));
            float p0 = (bits & 1u)        ? __builtin_amdgcn_exp2f(s[j][0]) : 0.f;
            float p1 = ((bits >> 1) & 1u) ? __builtin_amdgcn_exp2f(s[j][1]) : 0.f;
            float p2 = ((bits >> 2) & 1u) ? __builtin_amdgcn_exp2f(s[j][2]) : 0.f;
            float p3 = ((bits >> 3) & 1u) ? __builtin_amdgcn_exp2f(s[j][3]) : 0.f;
            f16x2 lo = pk2h(p0, p1);
            f16x2 hi = pk2h(p2, p3);
            pa[j] = __builtin_shufflevector(lo, hi, 0, 1, 2, 3);
        }

        // O += P V ; l += P ones   (K=16 fp16 MFMA, P straight from regs)
        #pragma unroll
        for (int j = 0; j < 4; j++) {
            ol = mfma_f16_k16(pa[j], ones, ol);
            #pragma unroll
            for (int jd = 0; jd < 4; jd++) {
                f16x4 bv = *(const f16x4*)&vs[jd * 16 + l16][j * 16 + quad * 4];
                o[jd] = mfma_f16_k16(pa[j], bv, o[jd]);
            }
        }
    }

    // epilogue: normalize (O and l share row layout quad*4+rr), stage in qs
    float linv[4];
    #pragma unroll
    for (int rr = 0; rr < 4; rr++) linv[rr] = 1.0f / ol[rr];
    short (*ps)[72] = (short(*)[72])&qs[w << 4];   // wave-private 16 rows
    #pragma unroll
    for (int jd = 0; jd < 4; jd++)
        #pragma unroll
        for (int rr = 0; rr < 4; rr++)
            ps[quad * 4 + rr][jd * 16 + l16] = f2b(o[jd][rr] * linv[rr]);

    #pragma unroll
    for (int k2 = 0; k2 < 2; k2++) {
        int row = (lane >> 3) + k2 * 8;
        int cc = (lane & 7) << 3;
        s16x8 vd = *(const s16x8*)&ps[row][cc];
        *(s16x8*)(xb + ((long)b * NQ + n0 + (w << 4) + row) * DIM + h * 64 + cc) = vd;
    }
}

// ---------------------------------------------------------------------------
extern "C" void kernel_launch(void* const* d_in, const int* in_sizes, int n_in,
                              void* d_out, int out_size, void* d_ws, size_t ws_size,
                              hipStream_t stream)
{
    const float* q     = (const float*)d_in[0];
    const float* kv    = (const float*)d_in[1];
    const float* Wq    = (const float*)d_in[2];
    const float* Wkv   = (const float*)d_in[3];
    const float* Wproj = (const float*)d_in[4];
    const float* bproj = (const float*)d_in[5];
    const int*   mask  = (const int*)d_in[6];
    float* out = (float*)d_out;

    char* ws = (char*)d_ws;
    short* q_bf   = (short*)ws; ws += (size_t)4096 * 768 * 2;
    short* kv_bf  = (short*)ws; ws += (size_t)8192 * 768 * 2;
    short* Wq_bf  = (short*)ws; ws += (size_t)768 * 768 * 2;
    short* Wkv_bf = (short*)ws; ws += (size_t)1536 * 768 * 2;
    short* Wp_bf  = (short*)ws; ws += (size_t)768 * 768 * 2;
    short* qp     = (short*)ws; ws += (size_t)4096 * 768 * 2;   // [B,H,N,64] bf16
    short* kk     = (short*)ws; ws += (size_t)8192 * 768 * 2;   // [B,H,M,64] bf16
    short* vt     = (short*)ws; ws += (size_t)8192 * 768 * 2;   // [B,H,64,M] fp16
    short* xb     = (short*)ws; ws += (size_t)4096 * 768 * 2;   // [B,N,768]  bf16
    unsigned char* mbytes = (unsigned char*)ws;                 // [B,N,M/8] = 1 MB

    prep_kernel<<<9856, 256, 0, stream>>>(q, kv, Wq, Wkv, Wproj, mask,
                                          q_bf, kv_bf, Wq_bf, Wkv_bf, Wp_bf, mbytes);
    gemm12_kernel<<<960, 256, 0, stream>>>(q_bf, Wq_bf, kv_bf, Wkv_bf, qp, kk, vt);
    attn_kernel<<<768, 256, 0, stream>>>(qp, kk, vt, (const unsigned*)mbytes, xb);
    gemm3_kernel<<<192, 256, 0, stream>>>(xb, Wp_bf, bproj, out);
}